// Round 1
// baseline (283.936 us; speedup 1.0000x reference)
//
#include <hip/hip_runtime.h>
#include <hip/hip_bf16.h>

#define IN_F   1024
#define OUT_F  1024
#define NCH    9                  // 8 spline channels + 1 base(silu) channel
#define KDIM   (IN_F * NCH)       // 9216
#define BATCH  8192

#define BM 128
#define BN 128
#define BK 32

typedef __attribute__((ext_vector_type(4))) float  f32x4;
typedef __attribute__((ext_vector_type(8))) __bf16 bf16x8;

typedef __attribute__((address_space(3))) unsigned short       lds_u16;
typedef const __attribute__((address_space(1))) unsigned short glb_u16;

__device__ inline unsigned short f2bf(float f) {
    union { float f; unsigned int u; } v; v.f = f;
    unsigned int u = v.u;
    unsigned int r = (u + 0x7FFFu + ((u >> 16) & 1u)) >> 16;   // RNE
    return (unsigned short)r;
}

// ---------------------------------------------------------------------------
// Kernel 1: combined weights  Wc[o][f*9 + c] (bf16)
//   c = 0..7 : spline_weight[o][f][c] * spline_scaler[o][f]
//   c = 8    : base_weight[o][f]
// ---------------------------------------------------------------------------
__global__ void wgt_kernel(const float* __restrict__ bw,
                           const float* __restrict__ sw,
                           const float* __restrict__ sc,
                           unsigned short* __restrict__ W) {
    int idx = blockIdx.x * blockDim.x + threadIdx.x;     // o*1024 + f
    if (idx >= OUT_F * IN_F) return;
    float scale = sc[idx];
    const float4* swp = (const float4*)(sw + (size_t)idx * 8);
    float4 w0 = swp[0], w1 = swp[1];
    int o = idx >> 10, f = idx & 1023;
    size_t base = (size_t)o * KDIM + (size_t)f * NCH;
    W[base + 0] = f2bf(w0.x * scale);
    W[base + 1] = f2bf(w0.y * scale);
    W[base + 2] = f2bf(w0.z * scale);
    W[base + 3] = f2bf(w0.w * scale);
    W[base + 4] = f2bf(w1.x * scale);
    W[base + 5] = f2bf(w1.y * scale);
    W[base + 6] = f2bf(w1.z * scale);
    W[base + 7] = f2bf(w1.w * scale);
    W[base + 8] = f2bf(bw[idx]);
}

// ---------------------------------------------------------------------------
// Kernel 2: activations  A[r][f*9 + c] (bf16)
//   c = 0..7 : cubic B-spline basis_c(x[r][f])   (uniform knots, closed form)
//   c = 8    : silu(x[r][f])
// Knots: g_i = -2.2 + 0.4*i, i=0..11. For x in [g_j, g_{j+1}), u=(x-g_j)/h,
// nonzero bases c=j-3..j with piece p=j-c:
//   p0=u^3/6, p1=(-3u^3+3u^2+3u+1)/6, p2=(3u^3-6u^2+4)/6, p3=(1-u)^3/6
// ---------------------------------------------------------------------------
__global__ void act_kernel(const float* __restrict__ x,
                           unsigned short* __restrict__ A,
                           int row0, int nrows) {
    int idx = blockIdx.x * blockDim.x + threadIdx.x;
    if (idx >= nrows * IN_F) return;
    int r = idx >> 10;
    int f = idx & 1023;
    float xv = x[(size_t)(row0 + r) * IN_F + f];

    float s = xv / (1.0f + __expf(-xv));                 // silu

    float t  = (xv + 2.2f) * 2.5f;                       // (x - g0)/h
    float jf = floorf(t);
    int   j  = (int)jf;
    float u  = t - jf;
    float u2 = u * u, u3 = u2 * u;
    float p0 = u3 * (1.0f / 6.0f);
    float p1 = (-3.0f * u3 + 3.0f * u2 + 3.0f * u + 1.0f) * (1.0f / 6.0f);
    float p2 = (3.0f * u3 - 6.0f * u2 + 4.0f) * (1.0f / 6.0f);
    float om = 1.0f - u;
    float p3 = om * om * om * (1.0f / 6.0f);
    bool valid = (xv >= -2.2f) && (xv < 2.2f);

    unsigned short outv[NCH];
#pragma unroll
    for (int c = 0; c < 8; ++c) {
        int p = j - c;
        float v = 0.0f;
        if (valid)
            v = (p == 0) ? p0 : (p == 1) ? p1 : (p == 2) ? p2 : (p == 3) ? p3 : 0.0f;
        outv[c] = f2bf(v);
    }
    outv[8] = f2bf(s);

    size_t base = (size_t)r * KDIM + (size_t)f * NCH;
#pragma unroll
    for (int c = 0; c < NCH; ++c) A[base + c] = outv[c];
}

// ---------------------------------------------------------------------------
// Kernel 3: GEMM  C[M][1024] = A[M][9216] (bf16) x Wc[1024][9216]^T (bf16)
// m97 structure: 128x128 tile, BK=32, 4 waves (2x2), 16x16x32 bf16 MFMA,
// global_load_lds width 16, single LDS buffer, 2 barriers per K-step.
// ---------------------------------------------------------------------------
__global__ __launch_bounds__(256) void gemm_bt(
    const unsigned short* __restrict__ A,
    const unsigned short* __restrict__ W,
    float* __restrict__ C) {
    __shared__ unsigned short lds[2 * BM * BK];          // 16 KiB: A tile | W tile
    unsigned short* ldsA = lds;
    unsigned short* ldsB = lds + BM * BK;

    const int tid  = threadIdx.x;
    const int wave = tid >> 6;
    const int lane = tid & 63;
    const int m0   = blockIdx.y * BM;
    const int n0   = blockIdx.x * BN;
    const int wr   = wave >> 1;                          // 0..1
    const int wc   = wave & 1;                           // 0..1

    f32x4 acc[4][4];
#pragma unroll
    for (int i = 0; i < 4; ++i)
#pragma unroll
        for (int jn = 0; jn < 4; ++jn) acc[i][jn] = (f32x4)(0.0f);

    // staging: tile is 512 chunks of 16B; thread handles chunk c0 (call 0)
    // and c1 (call 1) for both A and W tiles.
    const int c0 = wave * 64 + lane;                     // 0..255
    const int c1 = 256 + c0;                             // 256..511
    const int r0 = c0 >> 2, o0 = (c0 & 3) * 8;           // row / bf16-col
    const int r1 = c1 >> 2, o1 = (c1 & 3) * 8;

    const unsigned short* Ab0 = A + (size_t)(m0 + r0) * KDIM + o0;
    const unsigned short* Ab1 = A + (size_t)(m0 + r1) * KDIM + o1;
    const unsigned short* Wb0 = W + (size_t)(n0 + r0) * KDIM + o0;
    const unsigned short* Wb1 = W + (size_t)(n0 + r1) * KDIM + o1;

    // wave-uniform LDS bases (ushort units): 64 chunks * 8 ushort per wave-call
    const int ldsOff0 = wave * 512;
    const int ldsOff1 = 2048 + wave * 512;

    for (int k0 = 0; k0 < KDIM; k0 += BK) {
        __builtin_amdgcn_global_load_lds((glb_u16*)(Ab0 + k0), (lds_u16*)ldsA + ldsOff0, 16, 0, 0);
        __builtin_amdgcn_global_load_lds((glb_u16*)(Ab1 + k0), (lds_u16*)ldsA + ldsOff1, 16, 0, 0);
        __builtin_amdgcn_global_load_lds((glb_u16*)(Wb0 + k0), (lds_u16*)ldsB + ldsOff0, 16, 0, 0);
        __builtin_amdgcn_global_load_lds((glb_u16*)(Wb1 + k0), (lds_u16*)ldsB + ldsOff1, 16, 0, 0);
        __syncthreads();                                 // vmcnt(0) drain + barrier

        bf16x8 a[4], b[4];
#pragma unroll
        for (int mi = 0; mi < 4; ++mi)
            a[mi] = *(const bf16x8*)&ldsA[(wr * 64 + mi * 16 + (lane & 15)) * BK + (lane >> 4) * 8];
#pragma unroll
        for (int ni = 0; ni < 4; ++ni)
            b[ni] = *(const bf16x8*)&ldsB[(wc * 64 + ni * 16 + (lane & 15)) * BK + (lane >> 4) * 8];

#pragma unroll
        for (int mi = 0; mi < 4; ++mi)
#pragma unroll
            for (int ni = 0; ni < 4; ++ni)
                acc[mi][ni] = __builtin_amdgcn_mfma_f32_16x16x32_bf16(a[mi], b[ni], acc[mi][ni], 0, 0, 0);

        __syncthreads();                                 // protect LDS reuse
    }

    // epilogue: C/D layout col = lane&15, row = (lane>>4)*4 + r
    const int col   = n0 + wc * 64 + (lane & 15);
    const int rowb  = m0 + wr * 64 + (lane >> 4) * 4;
#pragma unroll
    for (int mi = 0; mi < 4; ++mi)
#pragma unroll
        for (int ni = 0; ni < 4; ++ni)
#pragma unroll
            for (int r = 0; r < 4; ++r)
                C[(size_t)(rowb + mi * 16 + r) * OUT_F + (col + ni * 16)] = acc[mi][ni][r];
}

// ---------------------------------------------------------------------------
extern "C" void kernel_launch(void* const* d_in, const int* in_sizes, int n_in,
                              void* d_out, int out_size, void* d_ws, size_t ws_size,
                              hipStream_t stream) {
    const float* x             = (const float*)d_in[0];
    const float* base_weight   = (const float*)d_in[1];
    const float* spline_weight = (const float*)d_in[2];
    const float* spline_scaler = (const float*)d_in[3];
    // d_in[4] = grid (uniform, constants hardcoded)
    float* out = (float*)d_out;

    unsigned short* Wc = (unsigned short*)d_ws;
    const size_t wbytes = (size_t)OUT_F * KDIM * sizeof(unsigned short);   // ~18.9 MB
    unsigned short* Abuf = (unsigned short*)((char*)d_ws + wbytes);

    // choose largest row-chunk (multiple of 128) that fits in remaining ws
    size_t avail = ws_size > wbytes ? ws_size - wbytes : 0;
    long max_rows = (long)(avail / ((size_t)KDIM * sizeof(unsigned short)));
    int chunk = (max_rows >= BATCH) ? BATCH : (int)((max_rows / 128) * 128);
    if (chunk <= 0) chunk = 128;

    wgt_kernel<<<(OUT_F * IN_F + 255) / 256, 256, 0, stream>>>(
        base_weight, spline_weight, spline_scaler, Wc);

    for (int r0 = 0; r0 < BATCH; r0 += chunk) {
        int rows = (BATCH - r0) < chunk ? (BATCH - r0) : chunk;
        act_kernel<<<(rows * IN_F + 255) / 256, 256, 0, stream>>>(x, Abuf, r0, rows);
        dim3 grid(OUT_F / BN, rows / BM);
        gemm_bt<<<grid, 256, 0, stream>>>(Abuf, Wc, out + (size_t)r0 * OUT_F);
    }
}

// Round 2
// 216.379 us; speedup vs baseline: 1.3122x; 1.3122x over previous
//
#include <hip/hip_runtime.h>
#include <hip/hip_bf16.h>

#define IN_F   1024
#define OUT_F  1024
#define NCH    9                  // 8 spline channels + 1 base(silu) channel
#define KDIM   (IN_F * NCH)       // 9216
#define BATCH  8192

// ---- GEMM geometry: 256x128 tile, BK=64, 8 waves (4M x 2N), 8-phase-style ----
#define BM 256
#define BN 128
#define BK 64
#define NT (KDIM / BK)            // 144 K-tiles
#define ABUF_OFF (BM * BK)        // 16384 u16
#define BUFSZ (BM * BK + BN * BK) // 24576 u16 per double-buffer half

typedef __attribute__((ext_vector_type(4))) float  f32x4;
typedef __attribute__((ext_vector_type(8))) __bf16 bf16x8;

typedef __attribute__((address_space(3))) unsigned short       lds_u16;
typedef const __attribute__((address_space(1))) unsigned short glb_u16;

__device__ inline unsigned short f2bf(float f) {
    union { float f; unsigned int u; } v; v.f = f;
    unsigned int u = v.u;
    unsigned int r = (u + 0x7FFFu + ((u >> 16) & 1u)) >> 16;   // RNE
    return (unsigned short)r;
}

// ---------------------------------------------------------------------------
// Kernel 1: combined weights  Wc[o][f*9 + c] (bf16)
// ---------------------------------------------------------------------------
__global__ void wgt_kernel(const float* __restrict__ bw,
                           const float* __restrict__ sw,
                           const float* __restrict__ sc,
                           unsigned short* __restrict__ W) {
    int idx = blockIdx.x * blockDim.x + threadIdx.x;     // o*1024 + f
    if (idx >= OUT_F * IN_F) return;
    float scale = sc[idx];
    const float4* swp = (const float4*)(sw + (size_t)idx * 8);
    float4 w0 = swp[0], w1 = swp[1];
    int o = idx >> 10, f = idx & 1023;
    size_t base = (size_t)o * KDIM + (size_t)f * NCH;
    W[base + 0] = f2bf(w0.x * scale);
    W[base + 1] = f2bf(w0.y * scale);
    W[base + 2] = f2bf(w0.z * scale);
    W[base + 3] = f2bf(w0.w * scale);
    W[base + 4] = f2bf(w1.x * scale);
    W[base + 5] = f2bf(w1.y * scale);
    W[base + 6] = f2bf(w1.z * scale);
    W[base + 7] = f2bf(w1.w * scale);
    W[base + 8] = f2bf(bw[idx]);
}

// ---------------------------------------------------------------------------
// Kernel 2: activations  A[r][f*9 + c] (bf16) — unchanged (validated round 1)
// ---------------------------------------------------------------------------
__global__ void act_kernel(const float* __restrict__ x,
                           unsigned short* __restrict__ A,
                           int row0, int nrows) {
    int idx = blockIdx.x * blockDim.x + threadIdx.x;
    if (idx >= nrows * IN_F) return;
    int r = idx >> 10;
    int f = idx & 1023;
    float xv = x[(size_t)(row0 + r) * IN_F + f];

    float s = xv / (1.0f + __expf(-xv));                 // silu

    float t  = (xv + 2.2f) * 2.5f;                       // (x - g0)/h
    float jf = floorf(t);
    int   j  = (int)jf;
    float u  = t - jf;
    float u2 = u * u, u3 = u2 * u;
    float p0 = u3 * (1.0f / 6.0f);
    float p1 = (-3.0f * u3 + 3.0f * u2 + 3.0f * u + 1.0f) * (1.0f / 6.0f);
    float p2 = (3.0f * u3 - 6.0f * u2 + 4.0f) * (1.0f / 6.0f);
    float om = 1.0f - u;
    float p3 = om * om * om * (1.0f / 6.0f);
    bool valid = (xv >= -2.2f) && (xv < 2.2f);

    unsigned short outv[NCH];
#pragma unroll
    for (int c = 0; c < 8; ++c) {
        int p = j - c;
        float v = 0.0f;
        if (valid)
            v = (p == 0) ? p0 : (p == 1) ? p1 : (p == 2) ? p2 : (p == 3) ? p3 : 0.0f;
        outv[c] = f2bf(v);
    }
    outv[8] = f2bf(s);

    size_t base = (size_t)r * KDIM + (size_t)f * NCH;
#pragma unroll
    for (int c = 0; c < NCH; ++c) A[base + c] = outv[c];
}

// ---------------------------------------------------------------------------
// Kernel 3: 8-phase-style GEMM  C[M][1024] = A[M][9216] x Wc[1024][9216]^T
// BM=256 BN=128 BK=64, 8 waves (4Mx2N), dbuf LDS 96KB, pre-swizzled staging
// (c16 ^= row&7 involution), 4 phases/K-tile, counted-vmcnt once per K-tile,
// setprio around MFMA clusters, XCD-chunked bijective block swizzle.
// ---------------------------------------------------------------------------

// stage decl: thread handles 16B chunk ci; row = ci>>3, col16 = ci&7;
// global src col is XOR-swizzled so linear LDS ends up swizzled.
#define DECLA(i) \
    const int ciA##i = (i) * 512 + tid; \
    const unsigned short* srcA##i = A + (size_t)(m0 + (ciA##i >> 3)) * KDIM \
        + ((((ciA##i) & 7) ^ ((ciA##i >> 3) & 7)) << 3); \
    const int ldsA##i = (ciA##i) << 3;

#define DECLB(i) \
    const int ciB##i = (i) * 512 + tid; \
    const unsigned short* srcB##i = W + (size_t)(n0 + (ciB##i >> 3)) * KDIM \
        + ((((ciB##i) & 7) ^ ((ciB##i >> 3) & 7)) << 3); \
    const int ldsB##i = ABUF_OFF + ((ciB##i) << 3);

#define STAGE_A(i) do { \
    __builtin_amdgcn_global_load_lds((glb_u16*)srcA##i, (lds_u16*)nb + ldsA##i, 16, 0, 0); \
    srcA##i += BK; } while (0)

#define STAGE_B(i) do { \
    __builtin_amdgcn_global_load_lds((glb_u16*)srcB##i, (lds_u16*)nb + ldsB##i, 16, 0, 0); \
    srcB##i += BK; } while (0)

// swizzled fragment read: row&7 == lane&7 (row = base16k + lane&15)
#define RDA(mi, kk) (*(const bf16x8*)&bufA[(rowa + (mi) * 16) * BK + ((((kk) * 4 + lhi) ^ l7) << 3)])
#define RDB(ni, kk) (*(const bf16x8*)&bufB[(rowb + (ni) * 16) * BK + ((((kk) * 4 + lhi) ^ l7) << 3)])

#define MM(mi, ni) do { \
    acc[mi][ni] = __builtin_amdgcn_mfma_f32_16x16x32_bf16(a##mi##0, b##ni##0, acc[mi][ni], 0, 0, 0); \
    acc[mi][ni] = __builtin_amdgcn_mfma_f32_16x16x32_bf16(a##mi##1, b##ni##1, acc[mi][ni], 0, 0, 0); \
} while (0)

__global__ __launch_bounds__(512, 2) void gemm_8p(
    const unsigned short* __restrict__ A,
    const unsigned short* __restrict__ W,
    float* __restrict__ C, int mblocks) {
    __shared__ unsigned short lds[2 * BUFSZ];            // 96 KiB

    const int tid  = threadIdx.x;
    const int wave = tid >> 6;
    const int lane = tid & 63;
    const int lm16 = lane & 15;
    const int lhi  = lane >> 4;
    const int l7   = lane & 7;

    // XCD-chunked bijective swizzle: nwg = mblocks*8 (divisible by 8)
    const int l  = (blockIdx.x & 7) * mblocks + (blockIdx.x >> 3);
    const int lm = l >> 3;                               // shares A-panel across ln
    const int ln = l & 7;
    const int m0 = lm * BM;
    const int n0 = ln * BN;

    const int wr = wave >> 1;                            // 0..3 (M)
    const int wc = wave & 1;                             // 0..1 (N)
    const int rowa = wr * 64 + lm16;
    const int rowb = wc * 64 + lm16;

    f32x4 acc[4][4];
#pragma unroll
    for (int i = 0; i < 4; ++i)
#pragma unroll
        for (int jn = 0; jn < 4; ++jn) acc[i][jn] = (f32x4)(0.0f);

    DECLA(0) DECLA(1) DECLA(2) DECLA(3)
    DECLB(0) DECLB(1)

    // prologue: stage K-tile 0 into buffer 0
    {
        unsigned short* nb = lds;
        STAGE_A(0); STAGE_A(1); STAGE_A(2); STAGE_A(3);
        STAGE_B(0); STAGE_B(1);
        asm volatile("s_waitcnt vmcnt(0)" ::: "memory");
        __builtin_amdgcn_s_barrier();
    }

    for (int t = 0; t < NT; ++t) {
        const unsigned short* bufA = lds + (t & 1) * BUFSZ;
        const unsigned short* bufB = bufA + ABUF_OFF;
        unsigned short* nb = lds + ((t & 1) ^ 1) * BUFSZ;
        const bool pf = (t + 1 < NT);

        bf16x8 a00, a01, a10, a11, a20, a21, a30, a31;
        bf16x8 b00, b01, b10, b11, b20, b21, b30, b31;

        // ---- phase 0: quadrant (mi 0-1, ni 0-1) ----
        a00 = RDA(0, 0); a01 = RDA(0, 1); a10 = RDA(1, 0); a11 = RDA(1, 1);
        b00 = RDB(0, 0); b01 = RDB(0, 1); b10 = RDB(1, 0); b11 = RDB(1, 1);
        if (pf) { STAGE_A(0); STAGE_A(1); }
        __builtin_amdgcn_s_barrier();
        __builtin_amdgcn_s_setprio(1);
        MM(0, 0); MM(0, 1); MM(1, 0); MM(1, 1);
        __builtin_amdgcn_s_setprio(0);
        __builtin_amdgcn_s_barrier();

        // ---- phase 1: quadrant (mi 0-1, ni 2-3) ----
        b20 = RDB(2, 0); b21 = RDB(2, 1); b30 = RDB(3, 0); b31 = RDB(3, 1);
        if (pf) { STAGE_A(2); STAGE_A(3); }
        __builtin_amdgcn_s_barrier();
        __builtin_amdgcn_s_setprio(1);
        MM(0, 2); MM(0, 3); MM(1, 2); MM(1, 3);
        __builtin_amdgcn_s_setprio(0);
        __builtin_amdgcn_s_barrier();

        // ---- phase 2: quadrant (mi 2-3, ni 2-3) ----
        a20 = RDA(2, 0); a21 = RDA(2, 1); a30 = RDA(3, 0); a31 = RDA(3, 1);
        if (pf) { STAGE_B(0); STAGE_B(1); }
        __builtin_amdgcn_s_barrier();
        __builtin_amdgcn_s_setprio(1);
        MM(2, 2); MM(2, 3); MM(3, 2); MM(3, 3);
        __builtin_amdgcn_s_setprio(0);
        __builtin_amdgcn_s_barrier();

        // ---- phase 3: quadrant (mi 2-3, ni 0-1), then tile-boundary drain ----
        __builtin_amdgcn_s_setprio(1);
        MM(2, 0); MM(2, 1); MM(3, 0); MM(3, 1);
        __builtin_amdgcn_s_setprio(0);
        asm volatile("s_waitcnt vmcnt(0)" ::: "memory");
        __builtin_amdgcn_s_barrier();
    }

    // epilogue: C/D layout col = lane&15, row = (lane>>4)*4 + r
    const int col0 = n0 + wc * 64 + lm16;
    const int row0 = m0 + wr * 64 + (lhi << 2);
#pragma unroll
    for (int mi = 0; mi < 4; ++mi)
#pragma unroll
        for (int ni = 0; ni < 4; ++ni)
#pragma unroll
            for (int r = 0; r < 4; ++r)
                C[(size_t)(row0 + mi * 16 + r) * OUT_F + (col0 + ni * 16)] = acc[mi][ni][r];
}

// ---------------------------------------------------------------------------
extern "C" void kernel_launch(void* const* d_in, const int* in_sizes, int n_in,
                              void* d_out, int out_size, void* d_ws, size_t ws_size,
                              hipStream_t stream) {
    const float* x             = (const float*)d_in[0];
    const float* base_weight   = (const float*)d_in[1];
    const float* spline_weight = (const float*)d_in[2];
    const float* spline_scaler = (const float*)d_in[3];
    // d_in[4] = grid (uniform, constants hardcoded)
    float* out = (float*)d_out;

    unsigned short* Wc = (unsigned short*)d_ws;
    const size_t wbytes = (size_t)OUT_F * KDIM * sizeof(unsigned short);   // ~18.9 MB
    unsigned short* Abuf = (unsigned short*)((char*)d_ws + wbytes);

    // largest row-chunk (multiple of BM=256) that fits in remaining ws
    size_t avail = ws_size > wbytes ? ws_size - wbytes : 0;
    long max_rows = (long)(avail / ((size_t)KDIM * sizeof(unsigned short)));
    int chunk = (max_rows >= BATCH) ? BATCH : (int)((max_rows / BM) * BM);
    if (chunk <= 0) chunk = BM;

    wgt_kernel<<<(OUT_F * IN_F + 255) / 256, 256, 0, stream>>>(
        base_weight, spline_weight, spline_scaler, Wc);

    for (int r0 = 0; r0 < BATCH; r0 += chunk) {
        int rows = (BATCH - r0) < chunk ? (BATCH - r0) : chunk;
        act_kernel<<<(rows * IN_F + 255) / 256, 256, 0, stream>>>(x, Abuf, r0, rows);
        int mblocks = rows / BM;
        gemm_8p<<<mblocks * 8, 512, 0, stream>>>(Abuf, Wc, out + (size_t)r0 * OUT_F, mblocks);
    }
}